// Round 1
// baseline (627.564 us; speedup 1.0000x reference)
//
#include <hip/hip_runtime.h>
#include <hip/hip_bf16.h>

typedef __bf16 bf16x8 __attribute__((ext_vector_type(8)));
typedef float f32x4 __attribute__((ext_vector_type(4)));

#define S_LEN 4096
#define DDIM  1024
#define QB    16
#define KB    128
#define DK    128

// ---------------- prep: q/k -> bf16 hi/lo planes ----------------
__global__ void prep_hilo(const float* __restrict__ q, const float* __restrict__ kk,
                          __bf16* __restrict__ qh, __bf16* __restrict__ ql,
                          __bf16* __restrict__ kh, __bf16* __restrict__ kl)
{
    const int n8 = (S_LEN * DDIM) / 8;
    for (int i = blockIdx.x * blockDim.x + threadIdx.x; i < n8; i += gridDim.x * blockDim.x) {
        float4 a = *(const float4*)(q + (size_t)i * 8);
        float4 b = *(const float4*)(q + (size_t)i * 8 + 4);
        float va[8] = {a.x, a.y, a.z, a.w, b.x, b.y, b.z, b.w};
        bf16x8 h, l;
#pragma unroll
        for (int j = 0; j < 8; ++j) {
            __bf16 hh = (__bf16)va[j];
            h[j] = hh;
            l[j] = (__bf16)(va[j] - (float)hh);
        }
        *(bf16x8*)(qh + (size_t)i * 8) = h;
        *(bf16x8*)(ql + (size_t)i * 8) = l;

        a = *(const float4*)(kk + (size_t)i * 8);
        b = *(const float4*)(kk + (size_t)i * 8 + 4);
        float vb[8] = {a.x, a.y, a.z, a.w, b.x, b.y, b.z, b.w};
#pragma unroll
        for (int j = 0; j < 8; ++j) {
            __bf16 hh = (__bf16)vb[j];
            h[j] = hh;
            l[j] = (__bf16)(vb[j] - (float)hh);
        }
        *(bf16x8*)(kh + (size_t)i * 8) = h;
        *(bf16x8*)(kl + (size_t)i * 8) = l;
    }
}

// ---------------- prep: V (S x DV) -> V^T bf16 (DV x S) ----------------
__global__ void prep_vt(const float* __restrict__ v, __bf16* __restrict__ vt)
{
    __shared__ float tile[32][33];
    const int t0 = blockIdx.x * 32;   // key dim
    const int d0 = blockIdx.y * 32;   // dv dim
    const int tx = threadIdx.x & 31;
    const int ty = threadIdx.x >> 5;  // 0..7
#pragma unroll
    for (int i = 0; i < 32; i += 8)
        tile[ty + i][tx] = v[(size_t)(t0 + ty + i) * DDIM + d0 + tx];
    __syncthreads();
#pragma unroll
    for (int i = 0; i < 32; i += 8)
        vt[(size_t)(d0 + ty + i) * S_LEN + t0 + tx] = (__bf16)tile[tx][ty + i];
}

// ---------------- prep: scale[t] = q[(t>>10)*1024, t&1023] ----------------
__global__ void prep_scale(const float* __restrict__ q, float* __restrict__ scale)
{
    const int j = blockIdx.x * blockDim.x + threadIdx.x;
    if (j < S_LEN) scale[j] = q[((size_t)(j >> 10) << 20) + (j & 1023)];
}

// ---------------- fused flash attention ----------------
__global__ __launch_bounds__(512, 2) void attn_kernel(
    const __bf16* __restrict__ qh, const __bf16* __restrict__ ql,
    const __bf16* __restrict__ kh, const __bf16* __restrict__ kl,
    const __bf16* __restrict__ vt, const float* __restrict__ scale,
    float* __restrict__ out)
{
    __shared__ __align__(16) __bf16 s_qh[QB][DDIM + 8];
    __shared__ __align__(16) __bf16 s_ql[QB][DDIM + 8];
    __shared__ __align__(16) __bf16 s_kh[KB][DK + 8];
    __shared__ __align__(16) __bf16 s_kl[KB][DK + 8];
    __shared__ __align__(16) float  s_S[QB][KB + 4];
    __shared__ __align__(16) __bf16 s_P[QB][KB + 8];
    __shared__ float s_m[QB], s_l[QB], s_a[QB];

    const int tid  = threadIdx.x;
    const int w    = tid >> 6;   // wave 0..7 (column sub-tile of S; dv slice of O)
    const int lane = tid & 63;
    const int q0   = blockIdx.x * QB;

    // Stage resident Q block (hi+lo), 2048 16B-units per plane
#pragma unroll
    for (int it = 0; it < 4; ++it) {
        int idx = tid + 512 * it;
        int r = idx >> 7, u = idx & 127;
        *(int4*)&s_qh[r][u * 8] = *(const int4*)(qh + (size_t)(q0 + r) * DDIM + u * 8);
        *(int4*)&s_ql[r][u * 8] = *(const int4*)(ql + (size_t)(q0 + r) * DDIM + u * 8);
    }
    if (tid < QB) { s_m[tid] = -1e30f; s_l[tid] = 0.f; }

    f32x4 o[8];
#pragma unroll
    for (int f = 0; f < 8; ++f) o[f] = (f32x4){0.f, 0.f, 0.f, 0.f};

    __syncthreads();

    const int arow = lane & 15;  // A-frag row / C-frag col
    const int aoct = lane >> 4;  // k-octet selector

    for (int kt = 0; kt < S_LEN / KB; ++kt) {
        f32x4 sacc = (f32x4){0.f, 0.f, 0.f, 0.f};
        for (int dc = 0; dc < DDIM / DK; ++dc) {
            __syncthreads();  // protect K buffers from previous readers
#pragma unroll
            for (int it = 0; it < 4; ++it) {
                int idx = tid + 512 * it;
                int r = idx >> 4, u = idx & 15;
                const size_t gsrc = (size_t)(kt * KB + r) * DDIM + dc * DK + u * 8;
                *(int4*)&s_kh[r][u * 8] = *(const int4*)(kh + gsrc);
                *(int4*)&s_kl[r][u * 8] = *(const int4*)(kl + gsrc);
            }
            __syncthreads();
#pragma unroll
            for (int ks = 0; ks < 4; ++ks) {
                bf16x8 a_h = *(const bf16x8*)&s_qh[arow][dc * DK + ks * 32 + aoct * 8];
                bf16x8 a_l = *(const bf16x8*)&s_ql[arow][dc * DK + ks * 32 + aoct * 8];
                bf16x8 b_h = *(const bf16x8*)&s_kh[w * 16 + arow][ks * 32 + aoct * 8];
                bf16x8 b_l = *(const bf16x8*)&s_kl[w * 16 + arow][ks * 32 + aoct * 8];
                sacc = __builtin_amdgcn_mfma_f32_16x16x32_bf16(a_h, b_h, sacc, 0, 0, 0);
                sacc = __builtin_amdgcn_mfma_f32_16x16x32_bf16(a_l, b_h, sacc, 0, 0, 0);
                sacc = __builtin_amdgcn_mfma_f32_16x16x32_bf16(a_h, b_l, sacc, 0, 0, 0);
            }
        }
        // apply per-column scale, spill S tile to LDS
        {
            const float sv = scale[kt * KB + w * 16 + arow];
#pragma unroll
            for (int i = 0; i < 4; ++i)
                s_S[aoct * 4 + i][w * 16 + arow] = sacc[i] * sv;
        }
        __syncthreads();
        // cooperative softmax: 16 rows x 32 threads, online m/l update
        {
            const int row = tid >> 5, sub = tid & 31;
            float v0 = s_S[row][sub], v1 = s_S[row][sub + 32];
            float v2 = s_S[row][sub + 64], v3 = s_S[row][sub + 96];
            float mx = fmaxf(fmaxf(v0, v1), fmaxf(v2, v3));
#pragma unroll
            for (int m = 16; m >= 1; m >>= 1) mx = fmaxf(mx, __shfl_xor(mx, m, 32));
            const float m_old = s_m[row];
            const float m_new = fmaxf(m_old, mx);
            float p0 = __expf(v0 - m_new), p1 = __expf(v1 - m_new);
            float p2 = __expf(v2 - m_new), p3 = __expf(v3 - m_new);
            float ls = p0 + p1 + p2 + p3;
#pragma unroll
            for (int m = 16; m >= 1; m >>= 1) ls += __shfl_xor(ls, m, 32);
            s_P[row][sub]      = (__bf16)p0;
            s_P[row][sub + 32] = (__bf16)p1;
            s_P[row][sub + 64] = (__bf16)p2;
            s_P[row][sub + 96] = (__bf16)p3;
            if (sub == 0) {
                const float alpha = __expf(m_old - m_new);  // first tile: exp(-1e30)=0
                s_a[row] = alpha;
                s_m[row] = m_new;
                s_l[row] = alpha * s_l[row] + ls;
            }
        }
        __syncthreads();
        // rescale O accumulator
#pragma unroll
        for (int i = 0; i < 4; ++i) {
            const float al = s_a[aoct * 4 + i];
#pragma unroll
            for (int f = 0; f < 8; ++f) o[f][i] *= al;
        }
        // PV: A = P (LDS), B = V^T direct from global (L2-resident)
#pragma unroll
        for (int ks = 0; ks < 4; ++ks) {
            bf16x8 a = *(const bf16x8*)&s_P[arow][ks * 32 + aoct * 8];
#pragma unroll
            for (int f = 0; f < 8; ++f) {
                const int dv = w * 128 + f * 16 + arow;
                bf16x8 b = *(const bf16x8*)(vt + (size_t)dv * S_LEN + kt * KB + ks * 32 + aoct * 8);
                o[f] = __builtin_amdgcn_mfma_f32_16x16x32_bf16(a, b, o[f], 0, 0, 0);
            }
        }
    }
    // epilogue: divide by l, store fp32
#pragma unroll
    for (int i = 0; i < 4; ++i) {
        const int r = aoct * 4 + i;
        const float rinv = 1.0f / s_l[r];
#pragma unroll
        for (int f = 0; f < 8; ++f)
            out[(size_t)(q0 + r) * DDIM + w * 128 + f * 16 + arow] = o[f][i] * rinv;
    }
}

extern "C" void kernel_launch(void* const* d_in, const int* in_sizes, int n_in,
                              void* d_out, int out_size, void* d_ws, size_t ws_size,
                              hipStream_t stream)
{
    const float* q = (const float*)d_in[0];
    const float* k = (const float*)d_in[1];
    const float* v = (const float*)d_in[2];
    float* out = (float*)d_out;

    const size_t PLANE = (size_t)S_LEN * DDIM * sizeof(__bf16);  // 8 MiB
    const size_t NEEDED = 5 * PLANE + S_LEN * sizeof(float);
    if (ws_size < NEEDED) return;  // workspace too small; fail loudly via poison output

    char* ws = (char*)d_ws;
    __bf16* qh = (__bf16*)(ws);
    __bf16* ql = (__bf16*)(ws + PLANE);
    __bf16* kh = (__bf16*)(ws + 2 * PLANE);
    __bf16* kl = (__bf16*)(ws + 3 * PLANE);
    __bf16* vt = (__bf16*)(ws + 4 * PLANE);
    float* scale = (float*)(ws + 5 * PLANE);

    prep_hilo<<<dim3(1024), dim3(256), 0, stream>>>(q, k, qh, ql, kh, kl);
    prep_vt<<<dim3(S_LEN / 32, DDIM / 32), dim3(256), 0, stream>>>(v, vt);
    prep_scale<<<dim3(4), dim3(1024), 0, stream>>>(q, scale);
    attn_kernel<<<dim3(S_LEN / QB), dim3(512), 0, stream>>>(qh, ql, kh, kl, vt, scale, out);
}

// Round 2
// 508.522 us; speedup vs baseline: 1.2341x; 1.2341x over previous
//
#include <hip/hip_runtime.h>
#include <hip/hip_bf16.h>

typedef __bf16 bf16x8 __attribute__((ext_vector_type(8)));
typedef __bf16 bf16x4 __attribute__((ext_vector_type(4)));
typedef float f32x4 __attribute__((ext_vector_type(4)));

#define S_LEN 4096
#define DDIM  1024
#define QB    64
#define KB    128

#define MFMA __builtin_amdgcn_mfma_f32_16x16x32_bf16

// ---------------- prep: q/k -> bf16 hi/lo planes ----------------
__global__ void prep_hilo(const float* __restrict__ q, const float* __restrict__ kk,
                          __bf16* __restrict__ qh, __bf16* __restrict__ ql,
                          __bf16* __restrict__ kh, __bf16* __restrict__ kl)
{
    const int n8 = (S_LEN * DDIM) / 8;
    for (int i = blockIdx.x * blockDim.x + threadIdx.x; i < n8; i += gridDim.x * blockDim.x) {
        float4 a = *(const float4*)(q + (size_t)i * 8);
        float4 b = *(const float4*)(q + (size_t)i * 8 + 4);
        float va[8] = {a.x, a.y, a.z, a.w, b.x, b.y, b.z, b.w};
        bf16x8 h, l;
#pragma unroll
        for (int j = 0; j < 8; ++j) {
            __bf16 hh = (__bf16)va[j];
            h[j] = hh;
            l[j] = (__bf16)(va[j] - (float)hh);
        }
        *(bf16x8*)(qh + (size_t)i * 8) = h;
        *(bf16x8*)(ql + (size_t)i * 8) = l;

        a = *(const float4*)(kk + (size_t)i * 8);
        b = *(const float4*)(kk + (size_t)i * 8 + 4);
        float vb[8] = {a.x, a.y, a.z, a.w, b.x, b.y, b.z, b.w};
#pragma unroll
        for (int j = 0; j < 8; ++j) {
            __bf16 hh = (__bf16)vb[j];
            h[j] = hh;
            l[j] = (__bf16)(vb[j] - (float)hh);
        }
        *(bf16x8*)(kh + (size_t)i * 8) = h;
        *(bf16x8*)(kl + (size_t)i * 8) = l;
    }
}

// ---------------- prep: V (S x DV) -> V^T bf16 (DV x S) ----------------
__global__ void prep_vt(const float* __restrict__ v, __bf16* __restrict__ vt)
{
    __shared__ float tile[32][33];
    const int t0 = blockIdx.x * 32;
    const int d0 = blockIdx.y * 32;
    const int tx = threadIdx.x & 31;
    const int ty = threadIdx.x >> 5;
#pragma unroll
    for (int i = 0; i < 32; i += 8)
        tile[ty + i][tx] = v[(size_t)(t0 + ty + i) * DDIM + d0 + tx];
    __syncthreads();
#pragma unroll
    for (int i = 0; i < 32; i += 8)
        vt[(size_t)(d0 + ty + i) * S_LEN + t0 + tx] = (__bf16)tile[tx][ty + i];
}

// ---------------- prep: scale[t] = q[(t>>10)*1024, t&1023] ----------------
__global__ void prep_scale(const float* __restrict__ q, float* __restrict__ scale)
{
    const int j = blockIdx.x * blockDim.x + threadIdx.x;
    if (j < S_LEN) scale[j] = q[((size_t)(j >> 10) << 20) + (j & 1023)];
}

// ---------------- async global->LDS, 16B per lane, wave-uniform LDS base ----
__device__ __forceinline__ void gl_lds16(const __bf16* g, __bf16* l)
{
    __builtin_amdgcn_global_load_lds(
        (const __attribute__((address_space(1))) void*)g,
        (__attribute__((address_space(3))) void*)l, 16, 0, 0);
}

// stage one K plane (128 keys x 128 elems bf16 = 32KB) into linear LDS, with
// the XOR-swizzle applied on the GLOBAL source (LDS dest stays linear).
__device__ __forceinline__ void stage_k_plane(__bf16* dst, const __bf16* src,
                                              int key0, int dc, int w, int lane)
{
#pragma unroll
    for (int c = 0; c < 4; ++c) {
        const int ubase = w * 256 + c * 64;                // 16B-unit base (wave-uniform)
        const int row = (ubase >> 4) + (lane >> 4);        // 0..127
        const int slot = lane & 15;
        const __bf16* g = src + (size_t)(key0 + row) * DDIM + dc * KB
                              + ((slot ^ (row & 7)) * 8);
        gl_lds16(g, dst + ubase * 8);
    }
}

// stage one Q chunk (64 rows x 128 elems, hi+lo planes, 16KB each)
__device__ __forceinline__ void stage_q_chunk(__bf16* dh, __bf16* dl,
                                              const __bf16* qh, const __bf16* ql,
                                              int q0, int dc, int w, int lane)
{
#pragma unroll
    for (int c = 0; c < 2; ++c) {
        const int ubase = w * 128 + c * 64;
        const int row = (ubase >> 4) + (lane >> 4);        // 0..63
        const int slot = lane & 15;
        const size_t goff = (size_t)(q0 + row) * DDIM + dc * KB + ((slot ^ (row & 7)) * 8);
        gl_lds16(qh + goff, dh + ubase * 8);
        gl_lds16(ql + goff, dl + ubase * 8);
    }
}

// swizzled LDS fragment read (row pitch 256B, XOR bits 4-6 with row&7)
__device__ __forceinline__ bf16x8 lfrag(const __bf16* base, int row, int col)
{
    int byte = row * 256 + col * 2;
    byte ^= (row & 7) << 4;
    return *reinterpret_cast<const bf16x8*>(reinterpret_cast<const char*>(base) + byte);
}

__device__ __forceinline__ void pstore(__bf16* base, int row, int key, __bf16 v)
{
    int byte = row * 256 + key * 2;
    byte ^= (row & 7) << 4;
    *reinterpret_cast<__bf16*>(reinterpret_cast<char*>(base) + byte) = v;
}

// ---------------- fused flash attention, key-split ----------------
__global__ __launch_bounds__(512, 2) void attn_kernel(
    const __bf16* __restrict__ qh, const __bf16* __restrict__ ql,
    const __bf16* __restrict__ kh, const __bf16* __restrict__ kl,
    const __bf16* __restrict__ vt, const float* __restrict__ scale,
    __bf16* __restrict__ part, float* __restrict__ ml, int KT)
{
    __shared__ __align__(16) __bf16 s_k[2][KB * KB];        // 64KB (dbuf, one plane)
    __shared__ __align__(16) __bf16 s_q[2][2][QB * KB];     // 64KB (dbuf x {hi,lo})
    __shared__ __align__(16) __bf16 s_P[QB * KB];           // 16KB
    __shared__ float s_pm[8][32], s_ps[8][32];
    __shared__ float s_run_m[QB], s_run_l[QB];

    const int tid = threadIdx.x;
    const int w = tid >> 6, lane = tid & 63;
    const int arow = lane & 15, aoct = lane >> 4;
    const int wr = w >> 2, wc = w & 3;                      // (wrs,wcs)=(2,4)
    const int split = blockIdx.x;
    const int q0 = blockIdx.y * QB;
    const int keys_base = split * (KT * KB);

    if (tid < QB) { s_run_m[tid] = -1e30f; s_run_l[tid] = 0.f; }

    f32x4 o[8][4];
#pragma unroll
    for (int fr = 0; fr < 8; ++fr)
#pragma unroll
        for (int cf = 0; cf < 4; ++cf) o[fr][cf] = (f32x4){0.f, 0.f, 0.f, 0.f};

    // prologue: K_hi[kt0,dc0] + Q[dc0]
    stage_k_plane(s_k[0], kh, keys_base, 0, w, lane);
    stage_q_chunk(s_q[0][0], s_q[0][1], qh, ql, q0, 0, w, lane);
    __syncthreads();

    int cur = 0;
    for (int kt = 0; kt < KT; ++kt) {
        const int key0 = keys_base + kt * KB;
        f32x4 sacc[2][2];
#pragma unroll
        for (int ri = 0; ri < 2; ++ri)
#pragma unroll
            for (int ni = 0; ni < 2; ++ni) sacc[ri][ni] = (f32x4){0.f, 0.f, 0.f, 0.f};

        for (int dc = 0; dc < 8; ++dc) {
            bf16x8 ah[2][4];
            const __bf16* sqh = s_q[dc & 1][0];
            const __bf16* sql = s_q[dc & 1][1];
            // ---- PHASE A: s_k[cur] = K_hi[dc]; prefetch K_lo[dc]
            stage_k_plane(s_k[cur ^ 1], kl, key0, dc, w, lane);
#pragma unroll
            for (int ks = 0; ks < 4; ++ks) {
                ah[0][ks] = lfrag(sqh, wr * 32 + arow,      ks * 32 + aoct * 8);
                ah[1][ks] = lfrag(sqh, wr * 32 + 16 + arow, ks * 32 + aoct * 8);
                bf16x8 al0 = lfrag(sql, wr * 32 + arow,      ks * 32 + aoct * 8);
                bf16x8 al1 = lfrag(sql, wr * 32 + 16 + arow, ks * 32 + aoct * 8);
                bf16x8 bh0 = lfrag(s_k[cur], wc * 32 + arow,      ks * 32 + aoct * 8);
                bf16x8 bh1 = lfrag(s_k[cur], wc * 32 + 16 + arow, ks * 32 + aoct * 8);
                sacc[0][0] = MFMA(ah[0][ks], bh0, sacc[0][0], 0, 0, 0);
                sacc[0][1] = MFMA(ah[0][ks], bh1, sacc[0][1], 0, 0, 0);
                sacc[1][0] = MFMA(ah[1][ks], bh0, sacc[1][0], 0, 0, 0);
                sacc[1][1] = MFMA(ah[1][ks], bh1, sacc[1][1], 0, 0, 0);
                sacc[0][0] = MFMA(al0, bh0, sacc[0][0], 0, 0, 0);
                sacc[0][1] = MFMA(al0, bh1, sacc[0][1], 0, 0, 0);
                sacc[1][0] = MFMA(al1, bh0, sacc[1][0], 0, 0, 0);
                sacc[1][1] = MFMA(al1, bh1, sacc[1][1], 0, 0, 0);
            }
            __syncthreads();
            cur ^= 1;
            // ---- PHASE B: s_k[cur] = K_lo[dc]; prefetch next K_hi (+Q)
            if (dc < 7) {
                stage_k_plane(s_k[cur ^ 1], kh, key0, dc + 1, w, lane);
                stage_q_chunk(s_q[(dc + 1) & 1][0], s_q[(dc + 1) & 1][1], qh, ql, q0, dc + 1, w, lane);
            } else if (kt + 1 < KT) {
                stage_k_plane(s_k[cur ^ 1], kh, key0 + KB, 0, w, lane);
                stage_q_chunk(s_q[0][0], s_q[0][1], qh, ql, q0, 0, w, lane);
            }
#pragma unroll
            for (int ks = 0; ks < 4; ++ks) {
                bf16x8 bl0 = lfrag(s_k[cur], wc * 32 + arow,      ks * 32 + aoct * 8);
                bf16x8 bl1 = lfrag(s_k[cur], wc * 32 + 16 + arow, ks * 32 + aoct * 8);
                sacc[0][0] = MFMA(ah[0][ks], bl0, sacc[0][0], 0, 0, 0);
                sacc[0][1] = MFMA(ah[0][ks], bl1, sacc[0][1], 0, 0, 0);
                sacc[1][0] = MFMA(ah[1][ks], bl0, sacc[1][0], 0, 0, 0);
                sacc[1][1] = MFMA(ah[1][ks], bl1, sacc[1][1], 0, 0, 0);
            }
            __syncthreads();
            cur ^= 1;
        }

        // ---------------- softmax (in-register, cross-wave stats via LDS) ----
        const float sv0 = scale[key0 + wc * 32 + arow];
        const float sv1 = scale[key0 + wc * 32 + 16 + arow];
        float x[2][2][4];
#pragma unroll
        for (int ri = 0; ri < 2; ++ri)
#pragma unroll
            for (int iv = 0; iv < 4; ++iv) {
                x[ri][0][iv] = sacc[ri][0][iv] * sv0;
                x[ri][1][iv] = sacc[ri][1][iv] * sv1;
            }
        float pmax[2][4];
#pragma unroll
        for (int ri = 0; ri < 2; ++ri)
#pragma unroll
            for (int iv = 0; iv < 4; ++iv) {
                float m = fmaxf(x[ri][0][iv], x[ri][1][iv]);
#pragma unroll
                for (int sh = 8; sh >= 1; sh >>= 1) m = fmaxf(m, __shfl_xor(m, sh));
                pmax[ri][iv] = m;
            }
        if (arow == 0) {
#pragma unroll
            for (int ri = 0; ri < 2; ++ri)
#pragma unroll
                for (int iv = 0; iv < 4; ++iv)
                    s_pm[w][ri * 16 + aoct * 4 + iv] = pmax[ri][iv];
        }
        __syncthreads();

        float mnew[2][4], mold[2][4], psum[2][4];
#pragma unroll
        for (int ri = 0; ri < 2; ++ri)
#pragma unroll
            for (int iv = 0; iv < 4; ++iv) {
                const int r = ri * 16 + aoct * 4 + iv;
                float mt = fmaxf(fmaxf(s_pm[wr * 4 + 0][r], s_pm[wr * 4 + 1][r]),
                                 fmaxf(s_pm[wr * 4 + 2][r], s_pm[wr * 4 + 3][r]));
                mold[ri][iv] = s_run_m[wr * 32 + r];
                mnew[ri][iv] = fmaxf(mold[ri][iv], mt);
                psum[ri][iv] = 0.f;
            }
#pragma unroll
        for (int ri = 0; ri < 2; ++ri)
#pragma unroll
            for (int iv = 0; iv < 4; ++iv) {
#pragma unroll
                for (int ni = 0; ni < 2; ++ni) {
                    float p = __expf(x[ri][ni][iv] - mnew[ri][iv]);
                    psum[ri][iv] += p;
                    pstore(s_P, wr * 32 + ri * 16 + aoct * 4 + iv,
                           wc * 32 + ni * 16 + arow, (__bf16)p);
                }
            }
#pragma unroll
        for (int ri = 0; ri < 2; ++ri)
#pragma unroll
            for (int iv = 0; iv < 4; ++iv) {
                float s = psum[ri][iv];
#pragma unroll
                for (int sh = 8; sh >= 1; sh >>= 1) s += __shfl_xor(s, sh);
                psum[ri][iv] = s;
            }
        if (arow == 0) {
#pragma unroll
            for (int ri = 0; ri < 2; ++ri)
#pragma unroll
                for (int iv = 0; iv < 4; ++iv)
                    s_ps[w][ri * 16 + aoct * 4 + iv] = psum[ri][iv];
        }
        // per-PV-column alphas (rows cf*16+arow), computed BEFORE s_run update
        float al_col[4];
#pragma unroll
        for (int cf = 0; cf < 4; ++cf) {
            const int r = cf * 16 + arow;
            const int g = cf >> 1;
            float mt = fmaxf(fmaxf(s_pm[g * 4 + 0][r & 31], s_pm[g * 4 + 1][r & 31]),
                             fmaxf(s_pm[g * 4 + 2][r & 31], s_pm[g * 4 + 3][r & 31]));
            float mo = s_run_m[r];
            al_col[cf] = __expf(mo - fmaxf(mo, mt));
        }
        float al_row[2][4];
#pragma unroll
        for (int ri = 0; ri < 2; ++ri)
#pragma unroll
            for (int iv = 0; iv < 4; ++iv)
                al_row[ri][iv] = __expf(mold[ri][iv] - mnew[ri][iv]);
        __syncthreads();

        // designated waves (wc==0) update running stats
        if (wc == 0 && arow == 0) {
#pragma unroll
            for (int ri = 0; ri < 2; ++ri)
#pragma unroll
                for (int iv = 0; iv < 4; ++iv) {
                    const int rl = ri * 16 + aoct * 4 + iv;
                    const int r = wr * 32 + rl;
                    float lsum = s_ps[wr * 4 + 0][rl] + s_ps[wr * 4 + 1][rl]
                               + s_ps[wr * 4 + 2][rl] + s_ps[wr * 4 + 3][rl];
                    s_run_l[r] = al_row[ri][iv] * s_run_l[r] + lsum;
                    s_run_m[r] = mnew[ri][iv];
                }
        }

        // rescale O accumulator
#pragma unroll
        for (int fr = 0; fr < 8; ++fr)
#pragma unroll
            for (int cf = 0; cf < 4; ++cf) {
                o[fr][cf][0] *= al_col[cf];
                o[fr][cf][1] *= al_col[cf];
                o[fr][cf][2] *= al_col[cf];
                o[fr][cf][3] *= al_col[cf];
            }

        // ---------------- PV:  O^T += V^T-frag x P^T-frag ----------------
#pragma unroll
        for (int kc = 0; kc < 4; ++kc) {
            bf16x8 bp[4];
#pragma unroll
            for (int cf = 0; cf < 4; ++cf)
                bp[cf] = lfrag(s_P, cf * 16 + arow, kc * 32 + aoct * 8);
#pragma unroll
            for (int fr = 0; fr < 8; ++fr) {
                const __bf16* vp = vt + (size_t)(w * 128 + fr * 16 + arow) * S_LEN
                                      + key0 + kc * 32 + aoct * 8;
                bf16x8 av = *(const bf16x8*)vp;
#pragma unroll
                for (int cf = 0; cf < 4; ++cf)
                    o[fr][cf] = MFMA(av, bp[cf], o[fr][cf], 0, 0, 0);
            }
        }
    }

    // ---------------- epilogue: unnormalized bf16 partial + (m,l) ----------
    __bf16* pb = part + (size_t)split * S_LEN * DDIM;
#pragma unroll
    for (int fr = 0; fr < 8; ++fr)
#pragma unroll
        for (int cf = 0; cf < 4; ++cf) {
            const int row = q0 + cf * 16 + arow;
            const int dv = w * 128 + fr * 16 + aoct * 4;
            bf16x4 v4 = {(__bf16)o[fr][cf][0], (__bf16)o[fr][cf][1],
                         (__bf16)o[fr][cf][2], (__bf16)o[fr][cf][3]};
            *(bf16x4*)(pb + (size_t)row * DDIM + dv) = v4;
        }
    __syncthreads();
    if (tid < QB) {
        float2 v = {s_run_m[tid], s_run_l[tid]};
        *(float2*)(ml + ((size_t)split * S_LEN + q0 + tid) * 2) = v;
    }
}

// ---------------- combine split partials ----------------
__global__ void combine_kernel(const __bf16* __restrict__ part, const float* __restrict__ ml,
                               float* __restrict__ out, int split)
{
    const int row = blockIdx.x;
    const int d0 = threadIdx.x * 4;
    float M = -3e38f;
    for (int s = 0; s < split; ++s)
        M = fmaxf(M, ml[((size_t)s * S_LEN + row) * 2]);
    float den = 0.f, n0 = 0.f, n1 = 0.f, n2 = 0.f, n3 = 0.f;
    for (int s = 0; s < split; ++s) {
        const float m = ml[((size_t)s * S_LEN + row) * 2];
        const float l = ml[((size_t)s * S_LEN + row) * 2 + 1];
        const float wgt = __expf(m - M);
        den += wgt * l;
        bf16x4 v = *(const bf16x4*)(part + (size_t)s * S_LEN * DDIM + (size_t)row * DDIM + d0);
        n0 += wgt * (float)v[0];
        n1 += wgt * (float)v[1];
        n2 += wgt * (float)v[2];
        n3 += wgt * (float)v[3];
    }
    const float inv = 1.f / den;
    f32x4 r = {n0 * inv, n1 * inv, n2 * inv, n3 * inv};
    *(f32x4*)(out + (size_t)row * DDIM + d0) = r;
}

extern "C" void kernel_launch(void* const* d_in, const int* in_sizes, int n_in,
                              void* d_out, int out_size, void* d_ws, size_t ws_size,
                              hipStream_t stream)
{
    const float* q = (const float*)d_in[0];
    const float* k = (const float*)d_in[1];
    const float* v = (const float*)d_in[2];
    float* out = (float*)d_out;

    const size_t PLANE = (size_t)S_LEN * DDIM * sizeof(__bf16);  // 8 MiB
    char* ws = (char*)d_ws;
    __bf16* qh = (__bf16*)(ws);
    __bf16* ql = (__bf16*)(ws + PLANE);
    __bf16* kh = (__bf16*)(ws + 2 * PLANE);
    __bf16* kl = (__bf16*)(ws + 3 * PLANE);
    __bf16* vt = (__bf16*)(ws + 4 * PLANE);
    float* scale = (float*)(ws + 5 * PLANE);
    const size_t mloff = 5 * PLANE + 64 * 1024;
    const size_t partoff = mloff + 512 * 1024;
    float* mlp = (float*)(ws + mloff);
    __bf16* part = (__bf16*)(ws + partoff);

    int split = 8;
    while (split > 1 && partoff + (size_t)split * S_LEN * DDIM * 2 > ws_size) split >>= 1;
    if (partoff + (size_t)split * S_LEN * DDIM * 2 > ws_size) return;  // ws too small: fail visibly
    const int KT = (S_LEN / split) / KB;

    prep_hilo<<<dim3(1024), dim3(256), 0, stream>>>(q, k, qh, ql, kh, kl);
    prep_vt<<<dim3(S_LEN / 32, DDIM / 32), dim3(256), 0, stream>>>(v, vt);
    prep_scale<<<dim3(4), dim3(1024), 0, stream>>>(q, scale);
    attn_kernel<<<dim3(split, S_LEN / QB), dim3(512), 0, stream>>>(
        qh, ql, kh, kl, vt, scale, part, mlp, KT);
    combine_kernel<<<dim3(S_LEN), dim3(256), 0, stream>>>(part, mlp, out, split);
}

// Round 4
// 173.503 us; speedup vs baseline: 3.6170x; 2.9309x over previous
//
#include <hip/hip_runtime.h>
#include <hip/hip_bf16.h>

typedef __bf16 bf16x8 __attribute__((ext_vector_type(8)));
typedef __bf16 bf16x4 __attribute__((ext_vector_type(4)));
typedef float f32x4 __attribute__((ext_vector_type(4)));

#define S_LEN 4096
#define DDIM  1024

#define MFMA __builtin_amdgcn_mfma_f32_16x16x32_bf16

#define BAR() do { asm volatile("" ::: "memory"); __builtin_amdgcn_s_barrier(); asm volatile("" ::: "memory"); } while (0)
#define VM6() asm volatile("s_waitcnt vmcnt(6)" ::: "memory")
#define VM0() asm volatile("s_waitcnt vmcnt(0)" ::: "memory")

__device__ __forceinline__ void gl_lds16(const __bf16* g, __bf16* l)
{
    __builtin_amdgcn_global_load_lds(
        (const __attribute__((address_space(1))) void*)g,
        (__attribute__((address_space(3))) void*)l, 16, 0, 0);
}

// ---------------- prep: q/k -> bf16 hi/lo planes ----------------
__global__ void prep_hilo(const float* __restrict__ q, const float* __restrict__ kk,
                          __bf16* __restrict__ qh, __bf16* __restrict__ ql,
                          __bf16* __restrict__ kh, __bf16* __restrict__ kl)
{
    const int n8 = (S_LEN * DDIM) / 8;
    for (int i = blockIdx.x * blockDim.x + threadIdx.x; i < n8; i += gridDim.x * blockDim.x) {
        float4 a = *(const float4*)(q + (size_t)i * 8);
        float4 b = *(const float4*)(q + (size_t)i * 8 + 4);
        float va[8] = {a.x, a.y, a.z, a.w, b.x, b.y, b.z, b.w};
        bf16x8 h, l;
#pragma unroll
        for (int j = 0; j < 8; ++j) {
            __bf16 hh = (__bf16)va[j];
            h[j] = hh;
            l[j] = (__bf16)(va[j] - (float)hh);
        }
        *(bf16x8*)(qh + (size_t)i * 8) = h;
        *(bf16x8*)(ql + (size_t)i * 8) = l;

        a = *(const float4*)(kk + (size_t)i * 8);
        b = *(const float4*)(kk + (size_t)i * 8 + 4);
        float vb[8] = {a.x, a.y, a.z, a.w, b.x, b.y, b.z, b.w};
#pragma unroll
        for (int j = 0; j < 8; ++j) {
            __bf16 hh = (__bf16)vb[j];
            h[j] = hh;
            l[j] = (__bf16)(vb[j] - (float)hh);
        }
        *(bf16x8*)(kh + (size_t)i * 8) = h;
        *(bf16x8*)(kl + (size_t)i * 8) = l;
    }
}

// ---------------- prep: V (S x DV) -> V^T bf16 (DV x S) ----------------
__global__ void prep_vt(const float* __restrict__ v, __bf16* __restrict__ vt)
{
    __shared__ float tile[32][33];
    const int t0 = blockIdx.x * 32;
    const int d0 = blockIdx.y * 32;
    const int tx = threadIdx.x & 31;
    const int ty = threadIdx.x >> 5;
#pragma unroll
    for (int i = 0; i < 32; i += 8)
        tile[ty + i][tx] = v[(size_t)(t0 + ty + i) * DDIM + d0 + tx];
    __syncthreads();
#pragma unroll
    for (int i = 0; i < 32; i += 8)
        vt[(size_t)(d0 + ty + i) * S_LEN + t0 + tx] = (__bf16)tile[tx][ty + i];
}

// ---------------- prep: scale[t] = q[(t>>10)*1024, t&1023] ----------------
__global__ void prep_scale(const float* __restrict__ q, float* __restrict__ scale)
{
    const int j = blockIdx.x * blockDim.x + threadIdx.x;
    if (j < S_LEN) scale[j] = q[((size_t)(j >> 10) << 20) + (j & 1023)];
}

// =====================================================================
// G1: S = (Q . K^T) * colscale  (3-term bf16 hi/lo split), 8-phase 256^2
// =====================================================================
__device__ __forceinline__ const __bf16* selA(const __bf16* qh, const __bf16* ql, int ps)
{ return ps == 1 ? ql : qh; }
__device__ __forceinline__ const __bf16* selB(const __bf16* kh, const __bf16* kl, int ps)
{ return ps == 2 ? kl : kh; }

// stage one 16KB region. RG 0,1 = A-halves; 2,3 = B-halves.
// LDS dest linear; XOR-swizzle (row&7) applied on GLOBAL source k-chunk.
template<int BUF, int RG>
__device__ __forceinline__ void stageG1(__bf16 (&lds)[2][4][8192], const __bf16* pl,
                                        int base, int koff, int w, int lane)
{
#pragma unroll
    for (int j = 0; j < 2; ++j) {
        const int ubase = (2 * w + j) * 64;
        const int u = ubase + lane;
        const int r = u >> 3, cu = u & 7;
        int grow;
        if (RG < 2) grow = base + ((r >> 6) << 7) + ((RG & 1) << 6) + (r & 63);
        else        grow = base + ((r >> 5) << 6) + ((RG & 1) << 5) + (r & 31);
        const __bf16* src = pl + (size_t)grow * DDIM + koff + ((cu ^ (r & 7)) << 3);
        gl_lds16(src, &lds[BUF][RG][0] + ubase * 8);
    }
}

template<int BUF, int MH>
__device__ __forceinline__ void rdA(bf16x8 (&a)[4][2], const __bf16 (&lds)[2][4][8192],
                                    int wr, int arow, int aoct)
{
#pragma unroll
    for (int mi = 0; mi < 4; ++mi)
#pragma unroll
        for (int ks = 0; ks < 2; ++ks) {
            const int lr = wr * 64 + mi * 16 + arow;
            const int cc = ks * 4 + aoct;
            a[mi][ks] = *(const bf16x8*)((const char*)&lds[BUF][MH][0]
                            + lr * 128 + ((cc ^ (lr & 7)) << 4));
        }
}

template<int BUF, int NH>
__device__ __forceinline__ void rdB(bf16x8 (&b)[2][2], const __bf16 (&lds)[2][4][8192],
                                    int wc, int arow, int aoct)
{
#pragma unroll
    for (int ni = 0; ni < 2; ++ni)
#pragma unroll
        for (int ks = 0; ks < 2; ++ks) {
            const int lr = wc * 32 + ni * 16 + arow;
            const int cc = ks * 4 + aoct;
            b[ni][ks] = *(const bf16x8*)((const char*)&lds[BUF][2 + NH][0]
                            + lr * 128 + ((cc ^ (lr & 7)) << 4));
        }
}

#define QMFMA(MH, NH, bb) \
    _Pragma("unroll") for (int ks = 0; ks < 2; ++ks) \
    _Pragma("unroll") for (int mi = 0; mi < 4; ++mi) \
    _Pragma("unroll") for (int ni = 0; ni < 2; ++ni) \
        acc[(MH)*4 + mi][(NH)*2 + ni] = MFMA(a[mi][ks], bb[ni][ks], acc[(MH)*4 + mi][(NH)*2 + ni], 0, 0, 0);

__global__ __launch_bounds__(512, 2) void gemm_qk(
    const __bf16* __restrict__ qh, const __bf16* __restrict__ ql,
    const __bf16* __restrict__ kh, const __bf16* __restrict__ kl,
    const float* __restrict__ scale, float* __restrict__ Sout)
{
    __shared__ __align__(16) __bf16 lds[2][4][8192];   // 128 KB

    const int tid = threadIdx.x;
    const int w = tid >> 6, lane = tid & 63;
    const int arow = lane & 15, aoct = lane >> 4;
    const int wr = w >> 2, wc = w & 3;
    // XCD swizzle (256 blocks, 8 XCDs -> 32-chunk per XCD; chunk = 2 B-panels)
    const int nb = (blockIdx.x & 7) * 32 + (blockIdx.x >> 3);
    const int m0 = (nb & 15) * 256, n0 = (nb >> 4) * 256;

    f32x4 acc[8][4];
#pragma unroll
    for (int i = 0; i < 8; ++i)
#pragma unroll
        for (int j = 0; j < 4; ++j) acc[i][j] = (f32x4){0.f, 0.f, 0.f, 0.f};

    // 48 K-tiles: tile t -> pass = t>>4 (plane pair), koff = (t&15)*64
    // prologue: tile0 full + tile1 {A0,B0,B1}
    stageG1<0, 0>(lds, selA(qh, ql, 0), m0, 0, w, lane);
    stageG1<0, 1>(lds, selA(qh, ql, 0), m0, 0, w, lane);
    stageG1<0, 2>(lds, selB(kh, kl, 0), n0, 0, w, lane);
    stageG1<0, 3>(lds, selB(kh, kl, 0), n0, 0, w, lane);
    stageG1<1, 0>(lds, selA(qh, ql, 0), m0, 64, w, lane);
    stageG1<1, 2>(lds, selB(kh, kl, 0), n0, 64, w, lane);
    stageG1<1, 3>(lds, selB(kh, kl, 0), n0, 64, w, lane);
    VM6(); BAR();

    for (int it = 0; it < 24; ++it) {
        const int t0 = 2 * it, t1 = 2 * it + 1;
        const bool last = (it == 23);
        const int ps1 = t1 >> 4, ko1 = (t1 & 15) << 6;
        const int ps2 = (t0 + 2) >> 4, ko2 = ((t0 + 2) & 15) << 6;
        const int ps3 = (t1 + 2) >> 4, ko3 = ((t1 + 2) & 15) << 6;
        bf16x8 a[4][2], b0[2][2], b1[2][2];

        // Ph1: tile t0 quad(0,0); stage A1 of t1 -> buf1
        rdA<0, 0>(a, lds, wr, arow, aoct);
        rdB<0, 0>(b0, lds, wc, arow, aoct);
        stageG1<1, 1>(lds, selA(qh, ql, ps1), m0, ko1, w, lane);
        BAR();
        __builtin_amdgcn_s_setprio(1); QMFMA(0, 0, b0); __builtin_amdgcn_s_setprio(0);
        BAR();
        // Ph2: quad(0,1); stage A0 of t0+2 -> buf0
        rdB<0, 1>(b1, lds, wc, arow, aoct);
        if (!last) stageG1<0, 0>(lds, selA(qh, ql, ps2), m0, ko2, w, lane);
        BAR();
        __builtin_amdgcn_s_setprio(1); QMFMA(0, 1, b1); __builtin_amdgcn_s_setprio(0);
        BAR();
        // Ph3: quad(1,0); stage B0 of t0+2
        rdA<0, 1>(a, lds, wr, arow, aoct);
        if (!last) stageG1<0, 2>(lds, selB(kh, kl, ps2), n0, ko2, w, lane);
        BAR();
        __builtin_amdgcn_s_setprio(1); QMFMA(1, 0, b0); __builtin_amdgcn_s_setprio(0);
        BAR();
        // Ph4: quad(1,1); stage B1 of t0+2; counted drain
        if (!last) stageG1<0, 3>(lds, selB(kh, kl, ps2), n0, ko2, w, lane);
        if (last) { VM0(); } else { VM6(); }
        BAR();
        __builtin_amdgcn_s_setprio(1); QMFMA(1, 1, b1); __builtin_amdgcn_s_setprio(0);
        BAR();
        // Ph5: tile t1 quad(0,0); stage A1 of t0+2
        rdA<1, 0>(a, lds, wr, arow, aoct);
        rdB<1, 0>(b0, lds, wc, arow, aoct);
        if (!last) stageG1<0, 1>(lds, selA(qh, ql, ps2), m0, ko2, w, lane);
        BAR();
        __builtin_amdgcn_s_setprio(1); QMFMA(0, 0, b0); __builtin_amdgcn_s_setprio(0);
        BAR();
        // Ph6: quad(0,1); stage A0 of t1+2 -> buf1
        rdB<1, 1>(b1, lds, wc, arow, aoct);
        if (!last) stageG1<1, 0>(lds, selA(qh, ql, ps3), m0, ko3, w, lane);
        BAR();
        __builtin_amdgcn_s_setprio(1); QMFMA(0, 1, b1); __builtin_amdgcn_s_setprio(0);
        BAR();
        // Ph7: quad(1,0); stage B0 of t1+2
        rdA<1, 1>(a, lds, wr, arow, aoct);
        if (!last) stageG1<1, 2>(lds, selB(kh, kl, ps3), n0, ko3, w, lane);
        BAR();
        __builtin_amdgcn_s_setprio(1); QMFMA(1, 0, b0); __builtin_amdgcn_s_setprio(0);
        BAR();
        // Ph8: quad(1,1); stage B1 of t1+2; counted drain
        if (!last) stageG1<1, 3>(lds, selB(kh, kl, ps3), n0, ko3, w, lane);
        if (last) { VM0(); } else { VM6(); }
        BAR();
        __builtin_amdgcn_s_setprio(1); QMFMA(1, 1, b1); __builtin_amdgcn_s_setprio(0);
        BAR();
    }

    // epilogue: apply per-column scale, write fp32 S
    const int nbase = n0 + wc * 64;
    float sc[4];
#pragma unroll
    for (int ni = 0; ni < 4; ++ni) sc[ni] = scale[nbase + ni * 16 + arow];
#pragma unroll
    for (int mi = 0; mi < 8; ++mi)
#pragma unroll
        for (int ni = 0; ni < 4; ++ni)
#pragma unroll
            for (int ii = 0; ii < 4; ++ii) {
                const int m = m0 + wr * 128 + mi * 16 + aoct * 4 + ii;
                Sout[(size_t)m * S_LEN + nbase + ni * 16 + arow] = acc[mi][ni][ii] * sc[ni];
            }
}

// =====================================================================
// softmax: rows of S (fp32) -> normalized bf16 P in-place (pitch 8192)
// =====================================================================
__global__ __launch_bounds__(256) void softmax_kernel(const float* __restrict__ S,
                                                      __bf16* __restrict__ P)
{
    __shared__ float red[8];
    const int row = blockIdx.x, tid = threadIdx.x;
    const int w = tid >> 6, lane = tid & 63;
    const float* sr = S + (size_t)row * S_LEN;
    float4 v[4];
#pragma unroll
    for (int c = 0; c < 4; ++c) v[c] = *(const float4*)(sr + c * 1024 + tid * 4);
    float mx = -3e38f;
#pragma unroll
    for (int c = 0; c < 4; ++c)
        mx = fmaxf(mx, fmaxf(fmaxf(v[c].x, v[c].y), fmaxf(v[c].z, v[c].w)));
#pragma unroll
    for (int sh = 32; sh >= 1; sh >>= 1) mx = fmaxf(mx, __shfl_xor(mx, sh));
    if (lane == 0) red[w] = mx;
    __syncthreads();
    mx = fmaxf(fmaxf(red[0], red[1]), fmaxf(red[2], red[3]));

    float e[4][4];
    float sum = 0.f;
#pragma unroll
    for (int c = 0; c < 4; ++c) {
        e[c][0] = __expf(v[c].x - mx); e[c][1] = __expf(v[c].y - mx);
        e[c][2] = __expf(v[c].z - mx); e[c][3] = __expf(v[c].w - mx);
        sum += (e[c][0] + e[c][1]) + (e[c][2] + e[c][3]);
    }
#pragma unroll
    for (int sh = 32; sh >= 1; sh >>= 1) sum += __shfl_xor(sum, sh);
    if (lane == 0) red[4 + w] = sum;
    __syncthreads();
    sum = (red[4] + red[5]) + (red[6] + red[7]);
    const float inv = 1.f / sum;
#pragma unroll
    for (int c = 0; c < 4; ++c) {
        bf16x4 o = {(__bf16)(e[c][0] * inv), (__bf16)(e[c][1] * inv),
                    (__bf16)(e[c][2] * inv), (__bf16)(e[c][3] * inv)};
        *(bf16x4*)(P + (size_t)row * 8192 + c * 1024 + tid * 4) = o;
    }
}

// =====================================================================
// G2: O = P . V  (A = P bf16 pitch 8192, B^T = vt 1024x4096), 128^2 2-phase
// =====================================================================
template<int BUF>
__device__ __forceinline__ void stageG2(__bf16 (&lds)[2][2][8192],
                                        const __bf16* __restrict__ P,
                                        const __bf16* __restrict__ vt,
                                        int m0, int n0, int t, int w, int lane)
{
#pragma unroll
    for (int j = 0; j < 4; ++j) {
        const int ubase = (4 * w + j) * 64;
        const int u = ubase + lane;
        const int r = u >> 3, cu = u & 7;
        const int kc = t * 64 + ((cu ^ (r & 7)) << 3);
        gl_lds16(P + (size_t)(m0 + r) * 8192 + kc, &lds[BUF][0][0] + ubase * 8);
        gl_lds16(vt + (size_t)(n0 + r) * S_LEN + kc, &lds[BUF][1][0] + ubase * 8);
    }
}

__global__ __launch_bounds__(256, 2) void gemm_pv(const __bf16* __restrict__ P,
                                                  const __bf16* __restrict__ vt,
                                                  float* __restrict__ out)
{
    __shared__ __align__(16) __bf16 lds[2][2][8192];   // 64 KB

    const int tid = threadIdx.x;
    const int w = tid >> 6, lane = tid & 63;
    const int arow = lane & 15, aoct = lane >> 4;
    const int wr = w >> 1, wc = w & 1;
    // swizzle: XCD x owns n-tile x (vt panel 1MB L2-resident)
    const int nb = (blockIdx.x & 7) * 32 + (blockIdx.x >> 3);
    const int m0 = (nb & 31) * 128, n0 = (nb >> 5) * 128;

    f32x4 acc[4][4];
#pragma unroll
    for (int i = 0; i < 4; ++i)
#pragma unroll
        for (int j = 0; j < 4; ++j) acc[i][j] = (f32x4){0.f, 0.f, 0.f, 0.f};

    stageG2<0>(lds, P, vt, m0, n0, 0, w, lane);
    VM0(); BAR();

    for (int t = 0; t < 64; ++t) {
        const int cur = t & 1;
        if (t < 63) {
            if (cur) stageG2<0>(lds, P, vt, m0, n0, t + 1, w, lane);
            else     stageG2<1>(lds, P, vt, m0, n0, t + 1, w, lane);
        }
        bf16x8 a[4][2], b[4][2];
#pragma unroll
        for (int mi = 0; mi < 4; ++mi)
#pragma unroll
            for (int ks = 0; ks < 2; ++ks) {
                const int lr = wr * 64 + mi * 16 + arow;
                const int cc = ks * 4 + aoct;
                a[mi][ks] = *(const bf16x8*)((const char*)&lds[cur][0][0]
                                + lr * 128 + ((cc ^ (lr & 7)) << 4));
            }
#pragma unroll
        for (int ni = 0; ni < 4; ++ni)
#pragma unroll
            for (int ks = 0; ks < 2; ++ks) {
                const int lr = wc * 64 + ni * 16 + arow;
                const int cc = ks * 4 + aoct;
                b[ni][ks] = *(const bf16x8*)((const char*)&lds[cur][1][0]
                                + lr * 128 + ((cc ^ (lr & 7)) << 4));
            }
        __builtin_amdgcn_s_setprio(1);
#pragma unroll
        for (int ks = 0; ks < 2; ++ks)
#pragma unroll
            for (int mi = 0; mi < 4; ++mi)
#pragma unroll
                for (int ni = 0; ni < 4; ++ni)
                    acc[mi][ni] = MFMA(a[mi][ks], b[ni][ks], acc[mi][ni], 0, 0, 0);
        __builtin_amdgcn_s_setprio(0);
        VM0(); BAR();
    }

#pragma unroll
    for (int mi = 0; mi < 4; ++mi)
#pragma unroll
        for (int ni = 0; ni < 4; ++ni)
#pragma unroll
            for (int ii = 0; ii < 4; ++ii) {
                const int m = m0 + wr * 64 + mi * 16 + aoct * 4 + ii;
                const int n = n0 + wc * 64 + ni * 16 + arow;
                out[(size_t)m * DDIM + n] = acc[mi][ni][ii];
            }
}

extern "C" void kernel_launch(void* const* d_in, const int* in_sizes, int n_in,
                              void* d_out, int out_size, void* d_ws, size_t ws_size,
                              hipStream_t stream)
{
    const float* q = (const float*)d_in[0];
    const float* k = (const float*)d_in[1];
    const float* v = (const float*)d_in[2];
    float* out = (float*)d_out;

    const size_t PLANE = (size_t)S_LEN * DDIM * sizeof(__bf16);        // 8 MiB
    const size_t SOFF  = 5 * PLANE + 64 * 1024;
    const size_t NEEDED = SOFF + (size_t)S_LEN * S_LEN * sizeof(float); // ~104 MiB
    if (ws_size < NEEDED) return;  // fail visibly (poisoned output)

    char* ws = (char*)d_ws;
    __bf16* qh = (__bf16*)(ws);
    __bf16* ql = (__bf16*)(ws + PLANE);
    __bf16* kh = (__bf16*)(ws + 2 * PLANE);
    __bf16* kl = (__bf16*)(ws + 3 * PLANE);
    __bf16* vt = (__bf16*)(ws + 4 * PLANE);
    float* scale = (float*)(ws + 5 * PLANE);
    float* Smat = (float*)(ws + SOFF);
    __bf16* P = (__bf16*)Smat;   // in-place, row pitch 8192 bf16

    prep_hilo<<<dim3(1024), dim3(256), 0, stream>>>(q, k, qh, ql, kh, kl);
    prep_vt<<<dim3(S_LEN / 32, DDIM / 32), dim3(256), 0, stream>>>(v, vt);
    prep_scale<<<dim3(4), dim3(1024), 0, stream>>>(q, scale);
    gemm_qk<<<dim3(256), dim3(512), 0, stream>>>(qh, ql, kh, kl, scale, Smat);
    softmax_kernel<<<dim3(S_LEN), dim3(256), 0, stream>>>(Smat, P);
    gemm_pv<<<dim3(256), dim3(256), 0, stream>>>(P, vt, out);
}

// Round 6
// 164.598 us; speedup vs baseline: 3.8127x; 1.0541x over previous
//
#include <hip/hip_runtime.h>
#include <hip/hip_bf16.h>

typedef __bf16 bf16x8 __attribute__((ext_vector_type(8)));
typedef __bf16 bf16x4 __attribute__((ext_vector_type(4)));
typedef float f32x4 __attribute__((ext_vector_type(4)));

#define S_LEN 4096
#define DDIM  1024

#define MFMA __builtin_amdgcn_mfma_f32_16x16x32_bf16

#define BAR() do { asm volatile("" ::: "memory"); __builtin_amdgcn_s_barrier(); asm volatile("" ::: "memory"); } while (0)
#define VM6() asm volatile("s_waitcnt vmcnt(6)" ::: "memory")
#define VM4() asm volatile("s_waitcnt vmcnt(4)" ::: "memory")
#define VM0() asm volatile("s_waitcnt vmcnt(0)" ::: "memory")

__device__ __forceinline__ void gl_lds16(const __bf16* g, __bf16* l)
{
    __builtin_amdgcn_global_load_lds(
        (const __attribute__((address_space(1))) void*)g,
        (__attribute__((address_space(3))) void*)l, 16, 0, 0);
}

// ---------------- prep: q/k -> bf16 hi/lo planes (+ scale gather) ----------
__global__ void prep_hilo(const float* __restrict__ q, const float* __restrict__ kk,
                          __bf16* __restrict__ qh, __bf16* __restrict__ ql,
                          __bf16* __restrict__ kh, __bf16* __restrict__ kl,
                          float* __restrict__ scale)
{
    const int gid = blockIdx.x * blockDim.x + threadIdx.x;
    if (gid < S_LEN) scale[gid] = q[((size_t)(gid >> 10) << 20) + (gid & 1023)];

    const int n8 = (S_LEN * DDIM) / 8;
    for (int i = gid; i < n8; i += gridDim.x * blockDim.x) {
        float4 a = *(const float4*)(q + (size_t)i * 8);
        float4 b = *(const float4*)(q + (size_t)i * 8 + 4);
        float va[8] = {a.x, a.y, a.z, a.w, b.x, b.y, b.z, b.w};
        bf16x8 h, l;
#pragma unroll
        for (int j = 0; j < 8; ++j) {
            __bf16 hh = (__bf16)va[j];
            h[j] = hh;
            l[j] = (__bf16)(va[j] - (float)hh);
        }
        *(bf16x8*)(qh + (size_t)i * 8) = h;
        *(bf16x8*)(ql + (size_t)i * 8) = l;

        a = *(const float4*)(kk + (size_t)i * 8);
        b = *(const float4*)(kk + (size_t)i * 8 + 4);
        float vb[8] = {a.x, a.y, a.z, a.w, b.x, b.y, b.z, b.w};
#pragma unroll
        for (int j = 0; j < 8; ++j) {
            __bf16 hh = (__bf16)vb[j];
            h[j] = hh;
            l[j] = (__bf16)(vb[j] - (float)hh);
        }
        *(bf16x8*)(kh + (size_t)i * 8) = h;
        *(bf16x8*)(kl + (size_t)i * 8) = l;
    }
}

// ---------------- prep: V (S x DV) -> V^T bf16 (DV x S) ----------------
__global__ void prep_vt(const float* __restrict__ v, __bf16* __restrict__ vt)
{
    __shared__ float tile[32][33];
    const int t0 = blockIdx.x * 32;
    const int d0 = blockIdx.y * 32;
    const int tx = threadIdx.x & 31;
    const int ty = threadIdx.x >> 5;
#pragma unroll
    for (int i = 0; i < 32; i += 8)
        tile[ty + i][tx] = v[(size_t)(t0 + ty + i) * DDIM + d0 + tx];
    __syncthreads();
#pragma unroll
    for (int i = 0; i < 32; i += 8)
        vt[(size_t)(d0 + ty + i) * S_LEN + t0 + tx] = (__bf16)tile[tx][ty + i];
}

// =====================================================================
// G1: S = (Q . K^T) * colscale  (3-term bf16 hi/lo split), 8-phase 256^2
// =====================================================================
__device__ __forceinline__ const __bf16* selA(const __bf16* qh, const __bf16* ql, int ps)
{ return ps == 1 ? ql : qh; }
__device__ __forceinline__ const __bf16* selB(const __bf16* kh, const __bf16* kl, int ps)
{ return ps == 2 ? kl : kh; }

// stage one 16KB region. RG 0,1 = A-halves; 2,3 = B-halves.
// LDS dest linear; XOR-swizzle (row&7) applied on GLOBAL source k-chunk.
template<int BUF, int RG>
__device__ __forceinline__ void stageG1(__bf16 (&lds)[2][4][8192], const __bf16* pl,
                                        int base, int koff, int w, int lane)
{
#pragma unroll
    for (int j = 0; j < 2; ++j) {
        const int ubase = (2 * w + j) * 64;
        const int u = ubase + lane;
        const int r = u >> 3, cu = u & 7;
        int grow;
        if (RG < 2) grow = base + ((r >> 6) << 7) + ((RG & 1) << 6) + (r & 63);
        else        grow = base + ((r >> 5) << 6) + ((RG & 1) << 5) + (r & 31);
        const __bf16* src = pl + (size_t)grow * DDIM + koff + ((cu ^ (r & 7)) << 3);
        gl_lds16(src, &lds[BUF][RG][0] + ubase * 8);
    }
}

template<int BUF, int MH>
__device__ __forceinline__ void rdA(bf16x8 (&a)[4][2], const __bf16 (&lds)[2][4][8192],
                                    int wr, int arow, int aoct)
{
#pragma unroll
    for (int mi = 0; mi < 4; ++mi)
#pragma unroll
        for (int ks = 0; ks < 2; ++ks) {
            const int lr = wr * 64 + mi * 16 + arow;
            const int cc = ks * 4 + aoct;
            a[mi][ks] = *(const bf16x8*)((const char*)&lds[BUF][MH][0]
                            + lr * 128 + ((cc ^ (lr & 7)) << 4));
        }
}

template<int BUF, int NH>
__device__ __forceinline__ void rdB(bf16x8 (&b)[2][2], const __bf16 (&lds)[2][4][8192],
                                    int wc, int arow, int aoct)
{
#pragma unroll
    for (int ni = 0; ni < 2; ++ni)
#pragma unroll
        for (int ks = 0; ks < 2; ++ks) {
            const int lr = wc * 32 + ni * 16 + arow;
            const int cc = ks * 4 + aoct;
            b[ni][ks] = *(const bf16x8*)((const char*)&lds[BUF][2 + NH][0]
                            + lr * 128 + ((cc ^ (lr & 7)) << 4));
        }
}

#define QMFMA(MH, NH, bb) \
    _Pragma("unroll") for (int ks = 0; ks < 2; ++ks) \
    _Pragma("unroll") for (int mi = 0; mi < 4; ++mi) \
    _Pragma("unroll") for (int ni = 0; ni < 2; ++ni) \
        acc[(MH)*4 + mi][(NH)*2 + ni] = MFMA(a[mi][ks], bb[ni][ks], acc[(MH)*4 + mi][(NH)*2 + ni], 0, 0, 0);

__global__ __launch_bounds__(512, 2) void gemm_qk(
    const __bf16* __restrict__ qh, const __bf16* __restrict__ ql,
    const __bf16* __restrict__ kh, const __bf16* __restrict__ kl,
    const float* __restrict__ scale, float* __restrict__ Sout)
{
    __shared__ __align__(16) __bf16 lds[2][4][8192];   // 128 KB

    const int tid = threadIdx.x;
    const int w = tid >> 6, lane = tid & 63;
    const int arow = lane & 15, aoct = lane >> 4;
    const int wr = w >> 2, wc = w & 3;
    // XCD swizzle (256 blocks, 8 XCDs -> 32-chunk per XCD; chunk = 2 B-panels)
    const int nb = (blockIdx.x & 7) * 32 + (blockIdx.x >> 3);
    const int m0 = (nb & 15) * 256, n0 = (nb >> 4) * 256;

    f32x4 acc[8][4];
#pragma unroll
    for (int i = 0; i < 8; ++i)
#pragma unroll
        for (int j = 0; j < 4; ++j) acc[i][j] = (f32x4){0.f, 0.f, 0.f, 0.f};

    // 48 K-tiles: tile t -> pass = t>>4 (plane pair), koff = (t&15)*64
    // prologue: tile0 full + tile1 {A0,B0,B1}
    stageG1<0, 0>(lds, selA(qh, ql, 0), m0, 0, w, lane);
    stageG1<0, 1>(lds, selA(qh, ql, 0), m0, 0, w, lane);
    stageG1<0, 2>(lds, selB(kh, kl, 0), n0, 0, w, lane);
    stageG1<0, 3>(lds, selB(kh, kl, 0), n0, 0, w, lane);
    stageG1<1, 0>(lds, selA(qh, ql, 0), m0, 64, w, lane);
    stageG1<1, 2>(lds, selB(kh, kl, 0), n0, 64, w, lane);
    stageG1<1, 3>(lds, selB(kh, kl, 0), n0, 64, w, lane);
    VM6(); BAR();

    for (int it = 0; it < 24; ++it) {
        const int t0 = 2 * it, t1 = 2 * it + 1;
        const bool last = (it == 23);
        const int ps1 = t1 >> 4, ko1 = (t1 & 15) << 6;
        const int ps2 = (t0 + 2) >> 4, ko2 = ((t0 + 2) & 15) << 6;
        const int ps3 = (t1 + 2) >> 4, ko3 = ((t1 + 2) & 15) << 6;
        bf16x8 a[4][2], b0[2][2], b1[2][2];

        // Ph1: tile t0 quad(0,0); stage A1 of t1 -> buf1
        rdA<0, 0>(a, lds, wr, arow, aoct);
        rdB<0, 0>(b0, lds, wc, arow, aoct);
        stageG1<1, 1>(lds, selA(qh, ql, ps1), m0, ko1, w, lane);
        BAR();
        __builtin_amdgcn_s_setprio(1); QMFMA(0, 0, b0); __builtin_amdgcn_s_setprio(0);
        BAR();
        // Ph2: quad(0,1); stage A0 of t0+2 -> buf0
        rdB<0, 1>(b1, lds, wc, arow, aoct);
        if (!last) stageG1<0, 0>(lds, selA(qh, ql, ps2), m0, ko2, w, lane);
        BAR();
        __builtin_amdgcn_s_setprio(1); QMFMA(0, 1, b1); __builtin_amdgcn_s_setprio(0);
        BAR();
        // Ph3: quad(1,0); stage B0 of t0+2
        rdA<0, 1>(a, lds, wr, arow, aoct);
        if (!last) stageG1<0, 2>(lds, selB(kh, kl, ps2), n0, ko2, w, lane);
        BAR();
        __builtin_amdgcn_s_setprio(1); QMFMA(1, 0, b0); __builtin_amdgcn_s_setprio(0);
        BAR();
        // Ph4: quad(1,1); stage B1 of t0+2; counted drain
        if (!last) stageG1<0, 3>(lds, selB(kh, kl, ps2), n0, ko2, w, lane);
        if (last) { VM0(); } else { VM6(); }
        BAR();
        __builtin_amdgcn_s_setprio(1); QMFMA(1, 1, b1); __builtin_amdgcn_s_setprio(0);
        BAR();
        // Ph5: tile t1 quad(0,0); stage A1 of t0+2
        rdA<1, 0>(a, lds, wr, arow, aoct);
        rdB<1, 0>(b0, lds, wc, arow, aoct);
        if (!last) stageG1<0, 1>(lds, selA(qh, ql, ps2), m0, ko2, w, lane);
        BAR();
        __builtin_amdgcn_s_setprio(1); QMFMA(0, 0, b0); __builtin_amdgcn_s_setprio(0);
        BAR();
        // Ph6: quad(0,1); stage A0 of t1+2 -> buf1
        rdB<1, 1>(b1, lds, wc, arow, aoct);
        if (!last) stageG1<1, 0>(lds, selA(qh, ql, ps3), m0, ko3, w, lane);
        BAR();
        __builtin_amdgcn_s_setprio(1); QMFMA(0, 1, b1); __builtin_amdgcn_s_setprio(0);
        BAR();
        // Ph7: quad(1,0); stage B0 of t1+2
        rdA<1, 1>(a, lds, wr, arow, aoct);
        if (!last) stageG1<1, 2>(lds, selB(kh, kl, ps3), n0, ko3, w, lane);
        BAR();
        __builtin_amdgcn_s_setprio(1); QMFMA(1, 0, b0); __builtin_amdgcn_s_setprio(0);
        BAR();
        // Ph8: quad(1,1); stage B1 of t1+2; counted drain
        if (!last) stageG1<1, 3>(lds, selB(kh, kl, ps3), n0, ko3, w, lane);
        if (last) { VM0(); } else { VM6(); }
        BAR();
        __builtin_amdgcn_s_setprio(1); QMFMA(1, 1, b1); __builtin_amdgcn_s_setprio(0);
        BAR();
    }

    // epilogue: apply per-column scale, write fp32 S
    const int nbase = n0 + wc * 64;
    float sc[4];
#pragma unroll
    for (int ni = 0; ni < 4; ++ni) sc[ni] = scale[nbase + ni * 16 + arow];
#pragma unroll
    for (int mi = 0; mi < 8; ++mi)
#pragma unroll
        for (int ni = 0; ni < 4; ++ni)
#pragma unroll
            for (int ii = 0; ii < 4; ++ii) {
                const int m = m0 + wr * 128 + mi * 16 + aoct * 4 + ii;
                Sout[(size_t)m * S_LEN + nbase + ni * 16 + arow] = acc[mi][ni][ii] * sc[ni];
            }
}

// =====================================================================
// softmax: rows of S (fp32) -> normalized bf16 P in-place (pitch 8192)
// =====================================================================
__global__ __launch_bounds__(256) void softmax_kernel(const float* __restrict__ S,
                                                      __bf16* __restrict__ P)
{
    __shared__ float red[8];
    const int row = blockIdx.x, tid = threadIdx.x;
    const int w = tid >> 6, lane = tid & 63;
    const float* sr = S + (size_t)row * S_LEN;
    float4 v[4];
#pragma unroll
    for (int c = 0; c < 4; ++c) v[c] = *(const float4*)(sr + c * 1024 + tid * 4);
    float mx = -3e38f;
#pragma unroll
    for (int c = 0; c < 4; ++c)
        mx = fmaxf(mx, fmaxf(fmaxf(v[c].x, v[c].y), fmaxf(v[c].z, v[c].w)));
#pragma unroll
    for (int sh = 32; sh >= 1; sh >>= 1) mx = fmaxf(mx, __shfl_xor(mx, sh));
    if (lane == 0) red[w] = mx;
    __syncthreads();
    mx = fmaxf(fmaxf(red[0], red[1]), fmaxf(red[2], red[3]));

    float e[4][4];
    float sum = 0.f;
#pragma unroll
    for (int c = 0; c < 4; ++c) {
        e[c][0] = __expf(v[c].x - mx); e[c][1] = __expf(v[c].y - mx);
        e[c][2] = __expf(v[c].z - mx); e[c][3] = __expf(v[c].w - mx);
        sum += (e[c][0] + e[c][1]) + (e[c][2] + e[c][3]);
    }
#pragma unroll
    for (int sh = 32; sh >= 1; sh >>= 1) sum += __shfl_xor(sum, sh);
    if (lane == 0) red[4 + w] = sum;
    __syncthreads();
    sum = (red[4] + red[5]) + (red[6] + red[7]);
    const float inv = 1.f / sum;
#pragma unroll
    for (int c = 0; c < 4; ++c) {
        bf16x4 o = {(__bf16)(e[c][0] * inv), (__bf16)(e[c][1] * inv),
                    (__bf16)(e[c][2] * inv), (__bf16)(e[c][3] * inv)};
        *(bf16x4*)(P + (size_t)row * 8192 + c * 1024 + tid * 4) = o;
    }
}

// =====================================================================
// G2: O = P . V  (A = P bf16 pitch 8192, B^T = vt 1024x4096)
// 128^2 tile, 512 threads, 3-buffer counted-vmcnt, TWO barriers/iter:
//   {ds_read A,B | stage t+2} BAR  MFMA  sched_barrier  VM4  BAR
// Region staged at iter t was read at t-1 -> two barriers + MFMA-forced
// lgkmcnt drain between read and overwrite-issue (gemm_qk-proven shape).
// =====================================================================
__device__ __forceinline__ void stagePV(__bf16* __restrict__ dst,
                                        const __bf16* __restrict__ P,
                                        const __bf16* __restrict__ vt,
                                        int m0, int n0, int t, int w, int lane)
{
    // dst = &lds[buf][0][0]; region 0 = A (16KB), region 1 = B (16KB)
#pragma unroll
    for (int j = 0; j < 2; ++j) {
        const int ubase = (2 * w + j) * 64;
        const int u = ubase + lane;
        const int r = u >> 3, cu = u & 7;
        const int kc = t * 64 + ((cu ^ (r & 7)) << 3);
        gl_lds16(P + (size_t)(m0 + r) * 8192 + kc, dst + ubase * 8);
        gl_lds16(vt + (size_t)(n0 + r) * S_LEN + kc, dst + 8192 + ubase * 8);
    }
}

__global__ __launch_bounds__(512, 1) void gemm_pv(const __bf16* __restrict__ P,
                                                  const __bf16* __restrict__ vt,
                                                  float* __restrict__ out)
{
    __shared__ __align__(16) __bf16 lds[3][2][8192];   // 96 KB, 3-deep

    const int tid = threadIdx.x;
    const int w = tid >> 6, lane = tid & 63;
    const int arow = lane & 15, aoct = lane >> 4;
    const int wr = w >> 2, wc = w & 3;                  // 2M x 4N waves
    // swizzle: XCD x owns n-panel x (vt panel 1MB L2-resident)
    const int nb = (blockIdx.x & 7) * 32 + (blockIdx.x >> 3);
    const int m0 = (nb & 31) * 128, n0 = (nb >> 5) * 128;

    f32x4 acc[4][2];
#pragma unroll
    for (int i = 0; i < 4; ++i)
#pragma unroll
        for (int j = 0; j < 2; ++j) acc[i][j] = (f32x4){0.f, 0.f, 0.f, 0.f};

    stagePV(&lds[0][0][0], P, vt, m0, n0, 0, w, lane);
    stagePV(&lds[1][0][0], P, vt, m0, n0, 1, w, lane);
    VM4(); BAR();

    int c0 = 0, c1 = 1, c2 = 2;
    for (int t = 0; t < 64; ++t) {
        const char* pa = (const char*)&lds[c0][0][0];
        const char* pb = (const char*)&lds[c0][1][0];
        bf16x8 a[4][2], b[2][2];
#pragma unroll
        for (int mi = 0; mi < 4; ++mi)
#pragma unroll
            for (int ks = 0; ks < 2; ++ks) {
                const int lr = wr * 64 + mi * 16 + arow;
                const int cc = ks * 4 + aoct;
                a[mi][ks] = *(const bf16x8*)(pa + lr * 128 + ((cc ^ (lr & 7)) << 4));
            }
#pragma unroll
        for (int ni = 0; ni < 2; ++ni)
#pragma unroll
            for (int ks = 0; ks < 2; ++ks) {
                const int lr = wc * 32 + ni * 16 + arow;
                const int cc = ks * 4 + aoct;
                b[ni][ks] = *(const bf16x8*)(pb + lr * 128 + ((cc ^ (lr & 7)) << 4));
            }
        if (t < 62) stagePV(&lds[c2][0][0], P, vt, m0, n0, t + 2, w, lane);
        BAR();
        __builtin_amdgcn_s_setprio(1);
#pragma unroll
        for (int ks = 0; ks < 2; ++ks)
#pragma unroll
            for (int mi = 0; mi < 4; ++mi)
#pragma unroll
                for (int ni = 0; ni < 2; ++ni)
                    acc[mi][ni] = MFMA(a[mi][ks], b[ni][ks], acc[mi][ni], 0, 0, 0);
        __builtin_amdgcn_s_setprio(0);
        __builtin_amdgcn_sched_barrier(0);   // pin MFMAs (and their lgkmcnt) here
        if (t <= 60) { VM4(); } else { VM0(); }
        BAR();
        const int tmp = c0; c0 = c1; c1 = c2; c2 = tmp;
    }

#pragma unroll
    for (int mi = 0; mi < 4; ++mi)
#pragma unroll
        for (int ni = 0; ni < 2; ++ni)
#pragma unroll
            for (int ii = 0; ii < 4; ++ii) {
                const int m = m0 + wr * 64 + mi * 16 + aoct * 4 + ii;
                const int n = n0 + wc * 32 + ni * 16 + arow;
                out[(size_t)m * DDIM + n] = acc[mi][ni][ii];
            }
}

extern "C" void kernel_launch(void* const* d_in, const int* in_sizes, int n_in,
                              void* d_out, int out_size, void* d_ws, size_t ws_size,
                              hipStream_t stream)
{
    const float* q = (const float*)d_in[0];
    const float* k = (const float*)d_in[1];
    const float* v = (const float*)d_in[2];
    float* out = (float*)d_out;

    const size_t PLANE = (size_t)S_LEN * DDIM * sizeof(__bf16);        // 8 MiB
    const size_t SOFF  = 5 * PLANE + 64 * 1024;
    const size_t NEEDED = SOFF + (size_t)S_LEN * S_LEN * sizeof(float); // ~104 MiB
    if (ws_size < NEEDED) return;  // fail visibly (poisoned output)

    char* ws = (char*)d_ws;
    __bf16* qh = (__bf16*)(ws);
    __bf16* ql = (__bf16*)(ws + PLANE);
    __bf16* kh = (__bf16*)(ws + 2 * PLANE);
    __bf16* kl = (__bf16*)(ws + 3 * PLANE);
    __bf16* vt = (__bf16*)(ws + 4 * PLANE);
    float* scale = (float*)(ws + 5 * PLANE);
    float* Smat = (float*)(ws + SOFF);
    __bf16* P = (__bf16*)Smat;   // in-place, row pitch 8192 bf16

    prep_hilo<<<dim3(1024), dim3(256), 0, stream>>>(q, k, qh, ql, kh, kl, scale);
    prep_vt<<<dim3(S_LEN / 32, DDIM / 32), dim3(256), 0, stream>>>(v, vt);
    gemm_qk<<<dim3(256), dim3(512), 0, stream>>>(qh, ql, kh, kl, scale, Smat);
    softmax_kernel<<<dim3(S_LEN), dim3(256), 0, stream>>>(Smat, P);
    gemm_pv<<<dim3(256), dim3(512), 0, stream>>>(P, vt, out);
}